// Round 3
// baseline (2025.589 us; speedup 1.0000x reference)
//
#include <hip/hip_runtime.h>
#include <hip/hip_bf16.h>

typedef __bf16 bf16_t;
typedef __attribute__((ext_vector_type(8))) __bf16 bf16x8;
typedef __attribute__((ext_vector_type(4))) __bf16 bf16x4;
typedef __attribute__((ext_vector_type(4))) float f32x4;

// ---------------- gcn_norm ----------------
__global__ void k_deg_init(int* __restrict__ deg, int n) {
    int i = blockIdx.x * blockDim.x + threadIdx.x;
    if (i < n) deg[i] = 1;               // self-loop contributes 1 to every node
}

__global__ void k_deg_count(const int* __restrict__ dst, int* __restrict__ deg, int E) {
    int e = blockIdx.x * blockDim.x + threadIdx.x;
    if (e < E) atomicAdd(&deg[dst[e]], 1);
}

__global__ void k_dinv(const int* __restrict__ deg, float* __restrict__ dinv, int n) {
    int i = blockIdx.x * blockDim.x + threadIdx.x;
    if (i < n) dinv[i] = rsqrtf((float)deg[i]);   // deg >= 1 always
}

__global__ void k_norm(const int* __restrict__ src, const int* __restrict__ dst,
                       const float* __restrict__ dinv, float* __restrict__ nrm, int E) {
    int e = blockIdx.x * blockDim.x + threadIdx.x;
    if (e < E) nrm[e] = dinv[src[e]] * dinv[dst[e]];
}

// ---------------- GEMM: C[M,N](bf16) = A[M,K](f32) @ B[K,N](f32) ----------
// one wave per 16x16 C tile, K-loop of 16x16x32 MFMAs, f32 operands cast to
// bf16 inline. B is tiny (<=128KB) and cache-hot.
// MFMA 16x16x32 layouts (HW-verified per guide):
//   A[m=lane&15][k=(lane>>4)*8+j], B[k=(lane>>4)*8+j][n=lane&15],
//   D: col=lane&15, row=(lane>>4)*4+reg
__global__ __launch_bounds__(256) void k_gemm_f32(
        const float* __restrict__ A, const float* __restrict__ B,
        bf16_t* __restrict__ C, int M, int N, int K) {
    int wave = (blockIdx.x * blockDim.x + threadIdx.x) >> 6;
    int lane = threadIdx.x & 63;
    int ntiles = N >> 4;
    int mt = wave / ntiles;
    int nt = wave - mt * ntiles;
    if (mt * 16 >= M) return;
    int m0 = mt << 4, n0 = nt << 4;
    int r16  = lane & 15;   // A row / B col / D col
    int quad = lane >> 4;   // 0..3
    f32x4 acc = {0.f, 0.f, 0.f, 0.f};
    for (int k0 = 0; k0 < K; k0 += 32) {
        const float* ap = A + (size_t)(m0 + r16) * K + k0 + quad * 8;
        bf16x8 a;
#pragma unroll
        for (int j = 0; j < 8; ++j) a[j] = (bf16_t)ap[j];
        const float* bp = B + (size_t)(k0 + quad * 8) * N + n0 + r16;
        bf16x8 b;
#pragma unroll
        for (int j = 0; j < 8; ++j) b[j] = (bf16_t)bp[(size_t)j * N];
        acc = __builtin_amdgcn_mfma_f32_16x16x32_bf16(a, b, acc, 0, 0, 0);
    }
#pragma unroll
    for (int r = 0; r < 4; ++r)
        C[(size_t)(m0 + quad * 4 + r) * N + n0 + r16] = (bf16_t)acc[r];
}

// ------- edge scatter-add: acc[dst] += X[src] * nrm, 4 feats/thread -------
template <int LOGF>   // features per node = 1<<LOGF
__global__ void k_agg4(const int* __restrict__ src, const int* __restrict__ dst,
                       const float* __restrict__ nrm, const bf16_t* __restrict__ X,
                       float* __restrict__ acc, long long total4) {
    long long idx = (long long)blockIdx.x * blockDim.x + threadIdx.x;
    if (idx >= total4) return;
    const int G = 1 << (LOGF - 2);            // 4-feature groups per edge
    int e = (int)(idx >> (LOGF - 2));
    int f = (int)(idx & (G - 1)) << 2;
    float w = nrm[e];
    bf16x4 x = *(const bf16x4*)(X + ((size_t)src[e] << LOGF) + f);
    float* ap = acc + ((size_t)dst[e] << LOGF) + f;
#pragma unroll
    for (int j = 0; j < 4; ++j) atomicAdd(ap + j, (float)x[j] * w);
}

// H = relu(Hacc + XW1 * dinv^2 (self-loop) + b1), in place (f32)
__global__ void k_fin1(float* __restrict__ Hacc, const bf16_t* __restrict__ XW1,
                       const float* __restrict__ dinv, const float* __restrict__ b1,
                       int total /* n*128 */) {
    int idx = blockIdx.x * blockDim.x + threadIdx.x;
    if (idx >= total) return;
    int i = idx >> 7, f = idx & 127;
    float d = dinv[i];
    float v = Hacc[idx] + (float)XW1[idx] * d * d + b1[f];
    Hacc[idx] = fmaxf(v, 0.0f);
}

// logits = Oacc + XW2*dinv^2 + b2 ; out = log_softmax(logits), f32 out
__global__ void k_fin2(const float* __restrict__ Oacc, const bf16_t* __restrict__ XW2,
                       const float* __restrict__ dinv, const float* __restrict__ b2,
                       float* __restrict__ out, int n) {
    int i = blockIdx.x * blockDim.x + threadIdx.x;
    if (i >= n) return;
    float d2 = dinv[i] * dinv[i];
    float v[32];
    float mx = -1e30f;
#pragma unroll
    for (int c = 0; c < 32; ++c) {
        v[c] = Oacc[i * 32 + c] + (float)XW2[i * 32 + c] * d2 + b2[c];
        mx = fmaxf(mx, v[c]);
    }
    float s = 0.f;
#pragma unroll
    for (int c = 0; c < 32; ++c) s += expf(v[c] - mx);
    float ls = logf(s);
#pragma unroll
    for (int c = 0; c < 32; ++c) out[i * 32 + c] = v[c] - mx - ls;
}

extern "C" void kernel_launch(void* const* d_in, const int* in_sizes, int n_in,
                              void* d_out, int out_size, void* d_ws, size_t ws_size,
                              hipStream_t stream) {
    const float* feat = (const float*)d_in[0];
    const int*   eidx = (const int*)d_in[1];
    const float* W1   = (const float*)d_in[2];
    const float* b1   = (const float*)d_in[3];
    const float* W2   = (const float*)d_in[4];
    const float* b2   = (const float*)d_in[5];
    float* out = (float*)d_out;

    const int FIN = 256, HID = 128, NCLS = 32;
    const int N = in_sizes[0] / FIN;   // 100000
    const int E = in_sizes[1] / 2;     // 800000
    const int* src = eidx;
    const int* dst = eidx + E;

    // workspace carve-up (256B aligned), ~81 MB total
    char* ws = (char*)d_ws;
    size_t o = 0;
    auto alloc = [&](size_t bytes) -> void* {
        void* p = ws + o;
        o = (o + bytes + 255) & ~(size_t)255;
        return p;
    };
    int*    deg  = (int*)   alloc((size_t)N * 4);
    float*  dinv = (float*) alloc((size_t)N * 4);
    float*  nrm  = (float*) alloc((size_t)E * 4);
    bf16_t* XW1  = (bf16_t*)alloc((size_t)N * HID * 2);   // 25.6 MB bf16
    float*  Hacc = (float*) alloc((size_t)N * HID * 4);   // 51.2 MB f32
    // layer-2 buffers alias XW1's region (XW1 dead after k_fin1):
    bf16_t* XW2  = XW1;                                    // N*32 bf16 (6.4 MB)
    float*  Oacc = (float*)((char*)XW1 + (size_t)N * NCLS * 2);  // N*32 f32

    const int T = 256;
    k_deg_init <<<(N + T - 1) / T, T, 0, stream>>>(deg, N);
    k_deg_count<<<(E + T - 1) / T, T, 0, stream>>>(dst, deg, E);
    k_dinv     <<<(N + T - 1) / T, T, 0, stream>>>(deg, dinv, N);
    k_norm     <<<(E + T - 1) / T, T, 0, stream>>>(src, dst, dinv, nrm, E);

    // layer 1: XW1 = bf16(feat @ W1)
    {
        int waves = (N / 16) * (HID / 16);           // 50000
        k_gemm_f32<<<waves / 4, T, 0, stream>>>(feat, W1, XW1, N, HID, FIN);
    }
    hipMemsetAsync(Hacc, 0, (size_t)N * HID * 4, stream);
    {
        long long total4 = (long long)E * (HID / 4); // 25.6M
        k_agg4<7><<<(int)((total4 + T - 1) / T), T, 0, stream>>>(src, dst, nrm, XW1, Hacc, total4);
    }
    k_fin1<<<(N * HID + T - 1) / T, T, 0, stream>>>(Hacc, XW1, dinv, b1, N * HID);

    // layer 2: XW2 = bf16(H @ W2)
    {
        int waves = (N / 16) * (NCLS / 16);          // 12500
        k_gemm_f32<<<waves / 4, T, 0, stream>>>(Hacc, W2, XW2, N, NCLS, HID);
    }
    hipMemsetAsync(Oacc, 0, (size_t)N * NCLS * 4, stream);
    {
        long long total4 = (long long)E * (NCLS / 4); // 6.4M
        k_agg4<5><<<(int)((total4 + T - 1) / T), T, 0, stream>>>(src, dst, nrm, XW2, Oacc, total4);
    }
    k_fin2<<<(N + T - 1) / T, T, 0, stream>>>(Oacc, XW2, dinv, b2, out, N);
}

// Round 4
// 630.182 us; speedup vs baseline: 3.2143x; 3.2143x over previous
//
#include <hip/hip_runtime.h>
#include <hip/hip_bf16.h>

typedef __bf16 bf16_t;
typedef __attribute__((ext_vector_type(8))) __bf16 bf16x8;
typedef __attribute__((ext_vector_type(2))) __bf16 bf16x2;
typedef __attribute__((ext_vector_type(4))) float f32x4;

// ---------------- degree / dinv ----------------
__global__ void k_deg_count(const int* __restrict__ dst, int* __restrict__ deg, int E) {
    int e = blockIdx.x * blockDim.x + threadIdx.x;
    if (e < E) atomicAdd(&deg[dst[e]], 1);
}

__global__ void k_dinv(const int* __restrict__ deg, float* __restrict__ dinv, int n) {
    int i = blockIdx.x * blockDim.x + threadIdx.x;
    if (i < n) dinv[i] = rsqrtf((float)(deg[i] + 1));  // +1 = self loop
}

// ---------------- exclusive scan of deg -> rowPtr (single block) ----------
__global__ __launch_bounds__(1024) void k_scan(const int* __restrict__ deg,
                                               int* __restrict__ rowPtr, int n) {
    __shared__ int sums[1024];
    int t = threadIdx.x;
    int chunk = (n + 1023) >> 10;
    int lo = t * chunk;
    int hi = min(n, lo + chunk);
    int s = 0;
    for (int i = lo; i < hi; ++i) s += deg[i];
    sums[t] = s;
    __syncthreads();
    for (int d = 1; d < 1024; d <<= 1) {           // Hillis-Steele inclusive
        int u = (t >= d) ? sums[t - d] : 0;
        __syncthreads();
        sums[t] += u;
        __syncthreads();
    }
    int run = sums[t] - s;                          // exclusive offset for chunk
    for (int i = lo; i < hi; ++i) { rowPtr[i] = run; run += deg[i]; }
    if (t == 1023) rowPtr[n] = sums[1023];          // = E
}

// ---------------- scatter edges into CSR, payload = {src, nrm} ------------
__global__ void k_scatter(const int* __restrict__ src, const int* __restrict__ dst,
                          const float* __restrict__ dinv, const int* __restrict__ rowPtr,
                          int* __restrict__ cursor, int2* __restrict__ edata, int E) {
    int e = blockIdx.x * blockDim.x + threadIdx.x;
    if (e >= E) return;
    int s = src[e], d = dst[e];
    int pos = rowPtr[d] + atomicAdd(&cursor[d], 1);
    int2 p; p.x = s; p.y = __float_as_int(dinv[s] * dinv[d]);
    edata[pos] = p;
}

// ---------------- GEMM: C[M,N](bf16) = A[M,K](f32) @ B[K,N](f32) ----------
// MFMA 16x16x32 layouts (HW-verified): A[m=lane&15][k=quad*8+j],
// B[k=quad*8+j][n=lane&15], D: col=lane&15, row=quad*4+reg
__global__ __launch_bounds__(256) void k_gemm_f32(
        const float* __restrict__ A, const float* __restrict__ B,
        bf16_t* __restrict__ C, int M, int N, int K) {
    int wave = (blockIdx.x * blockDim.x + threadIdx.x) >> 6;
    int lane = threadIdx.x & 63;
    int ntiles = N >> 4;
    int mt = wave / ntiles;
    int nt = wave - mt * ntiles;
    if (mt * 16 >= M) return;
    int m0 = mt << 4, n0 = nt << 4;
    int r16  = lane & 15;
    int quad = lane >> 4;
    f32x4 acc = {0.f, 0.f, 0.f, 0.f};
    for (int k0 = 0; k0 < K; k0 += 32) {
        const float* ap = A + (size_t)(m0 + r16) * K + k0 + quad * 8;
        bf16x8 a;
#pragma unroll
        for (int j = 0; j < 8; ++j) a[j] = (bf16_t)ap[j];
        const float* bp = B + (size_t)(k0 + quad * 8) * N + n0 + r16;
        bf16x8 b;
#pragma unroll
        for (int j = 0; j < 8; ++j) b[j] = (bf16_t)bp[(size_t)j * N];
        acc = __builtin_amdgcn_mfma_f32_16x16x32_bf16(a, b, acc, 0, 0, 0);
    }
#pragma unroll
    for (int r = 0; r < 4; ++r)
        C[(size_t)(m0 + quad * 4 + r) * N + n0 + r16] = (bf16_t)acc[r];
}

// same but A is bf16 (vectorized 16B loads)
__global__ __launch_bounds__(256) void k_gemm_a16(
        const bf16_t* __restrict__ A, const float* __restrict__ B,
        bf16_t* __restrict__ C, int M, int N, int K) {
    int wave = (blockIdx.x * blockDim.x + threadIdx.x) >> 6;
    int lane = threadIdx.x & 63;
    int ntiles = N >> 4;
    int mt = wave / ntiles;
    int nt = wave - mt * ntiles;
    if (mt * 16 >= M) return;
    int m0 = mt << 4, n0 = nt << 4;
    int r16  = lane & 15;
    int quad = lane >> 4;
    f32x4 acc = {0.f, 0.f, 0.f, 0.f};
    for (int k0 = 0; k0 < K; k0 += 32) {
        bf16x8 a = *(const bf16x8*)(A + (size_t)(m0 + r16) * K + k0 + quad * 8);
        const float* bp = B + (size_t)(k0 + quad * 8) * N + n0 + r16;
        bf16x8 b;
#pragma unroll
        for (int j = 0; j < 8; ++j) b[j] = (bf16_t)bp[(size_t)j * N];
        acc = __builtin_amdgcn_mfma_f32_16x16x32_bf16(a, b, acc, 0, 0, 0);
    }
#pragma unroll
    for (int r = 0; r < 4; ++r)
        C[(size_t)(m0 + quad * 4 + r) * N + n0 + r16] = (bf16_t)acc[r];
}

// ------- layer-1 aggregate (CSR): one wave per node, 2 feats/lane ---------
// H[i] = relu( sum_e nrm*XW1[src] + dinv[i]^2*XW1[i] + b1 ), bf16 out
__global__ __launch_bounds__(256) void k_agg1(
        const int* __restrict__ rowPtr, const int2* __restrict__ edata,
        const bf16_t* __restrict__ XW1, const float* __restrict__ dinv,
        const float* __restrict__ b1, bf16_t* __restrict__ H, int n) {
    int wave = (blockIdx.x * blockDim.x + threadIdx.x) >> 6;
    if (wave >= n) return;
    int lane = threadIdx.x & 63;
    int f = lane << 1;
    int r0 = rowPtr[wave], r1 = rowPtr[wave + 1];
    float a0 = 0.f, a1 = 0.f, c0 = 0.f, c1 = 0.f;
    int k = r0;
    for (; k + 1 < r1; k += 2) {           // 2-edge unroll for ILP
        int2 e0 = edata[k], e1 = edata[k + 1];
        float w0 = __int_as_float(e0.y), w1 = __int_as_float(e1.y);
        bf16x2 x0 = *(const bf16x2*)(XW1 + ((size_t)e0.x << 7) + f);
        bf16x2 x1 = *(const bf16x2*)(XW1 + ((size_t)e1.x << 7) + f);
        a0 += (float)x0[0] * w0; a1 += (float)x0[1] * w0;
        c0 += (float)x1[0] * w1; c1 += (float)x1[1] * w1;
    }
    if (k < r1) {
        int2 e0 = edata[k];
        float w0 = __int_as_float(e0.y);
        bf16x2 x0 = *(const bf16x2*)(XW1 + ((size_t)e0.x << 7) + f);
        a0 += (float)x0[0] * w0; a1 += (float)x0[1] * w0;
    }
    float d = dinv[wave], d2 = d * d;
    bf16x2 xs = *(const bf16x2*)(XW1 + ((size_t)wave << 7) + f);
    float v0 = a0 + c0 + (float)xs[0] * d2 + b1[f];
    float v1 = a1 + c1 + (float)xs[1] * d2 + b1[f + 1];
    bf16x2 h;
    h[0] = (bf16_t)fmaxf(v0, 0.f);
    h[1] = (bf16_t)fmaxf(v1, 0.f);
    *(bf16x2*)(H + ((size_t)wave << 7) + f) = h;
}

// ------- layer-2 aggregate + log_softmax: one wave per node ----------------
// f = lane&31, halves process alternate edges; combine via shfl_xor(32).
__global__ __launch_bounds__(256) void k_agg2(
        const int* __restrict__ rowPtr, const int2* __restrict__ edata,
        const bf16_t* __restrict__ XW2, const float* __restrict__ dinv,
        const float* __restrict__ b2, float* __restrict__ out, int n) {
    int wave = (blockIdx.x * blockDim.x + threadIdx.x) >> 6;
    if (wave >= n) return;
    int lane = threadIdx.x & 63;
    int f = lane & 31, h = lane >> 5;
    int r0 = rowPtr[wave], r1 = rowPtr[wave + 1];
    float acc = 0.f;
    for (int k = r0 + h; k < r1; k += 2) {
        int2 e = edata[k];
        float w = __int_as_float(e.y);
        acc += (float)XW2[((size_t)e.x << 5) + f] * w;
    }
    acc += __shfl_xor(acc, 32);
    float d = dinv[wave];
    float v = acc + (float)XW2[((size_t)wave << 5) + f] * d * d + b2[f];
    float mx = v;
#pragma unroll
    for (int m = 16; m >= 1; m >>= 1) mx = fmaxf(mx, __shfl_xor(mx, m));
    float s = expf(v - mx);
#pragma unroll
    for (int m = 16; m >= 1; m >>= 1) s += __shfl_xor(s, m);
    if (lane < 32) out[((size_t)wave << 5) + f] = v - mx - logf(s);
}

extern "C" void kernel_launch(void* const* d_in, const int* in_sizes, int n_in,
                              void* d_out, int out_size, void* d_ws, size_t ws_size,
                              hipStream_t stream) {
    const float* feat = (const float*)d_in[0];
    const int*   eidx = (const int*)d_in[1];
    const float* W1   = (const float*)d_in[2];
    const float* b1   = (const float*)d_in[3];
    const float* W2   = (const float*)d_in[4];
    const float* b2   = (const float*)d_in[5];
    float* out = (float*)d_out;

    const int FIN = 256, HID = 128, NCLS = 32;
    const int N = in_sizes[0] / FIN;   // 100000
    const int E = in_sizes[1] / 2;     // 800000
    const int* src = eidx;
    const int* dst = eidx + E;

    // workspace carve-up (256B aligned), ~59 MB total
    char* ws = (char*)d_ws;
    size_t o = 0;
    auto alloc = [&](size_t bytes) -> void* {
        void* p = ws + o;
        o = (o + bytes + 255) & ~(size_t)255;
        return p;
    };
    int*    deg    = (int*)   alloc((size_t)N * 4);
    float*  dinv   = (float*) alloc((size_t)N * 4);
    int*    rowPtr = (int*)   alloc((size_t)(N + 1) * 4);
    int*    cursor = (int*)   alloc((size_t)N * 4);
    int2*   edata  = (int2*)  alloc((size_t)E * 8);        // 6.4 MB
    bf16_t* XW1    = (bf16_t*)alloc((size_t)N * HID * 2);  // 25.6 MB
    bf16_t* H      = (bf16_t*)alloc((size_t)N * HID * 2);  // 25.6 MB
    bf16_t* XW2    = XW1;   // alias: XW1 dead after k_agg1

    const int T = 256;
    hipMemsetAsync(deg, 0, (size_t)N * 4, stream);
    hipMemsetAsync(cursor, 0, (size_t)N * 4, stream);
    k_deg_count<<<(E + T - 1) / T, T, 0, stream>>>(dst, deg, E);
    k_dinv     <<<(N + T - 1) / T, T, 0, stream>>>(deg, dinv, N);
    k_scan     <<<1, 1024, 0, stream>>>(deg, rowPtr, N);
    k_scatter  <<<(E + T - 1) / T, T, 0, stream>>>(src, dst, dinv, rowPtr, cursor, edata, E);

    // layer 1: XW1 = bf16(feat @ W1)
    {
        int waves = (N / 16) * (HID / 16);           // 50000
        k_gemm_f32<<<waves / 4, T, 0, stream>>>(feat, W1, XW1, N, HID, FIN);
    }
    k_agg1<<<(N * 64 + T - 1) / T, T, 0, stream>>>(rowPtr, edata, XW1, dinv, b1, H, N);

    // layer 2: XW2 = bf16(H @ W2)
    {
        int waves = (N / 16) * (NCLS / 16);          // 12500
        k_gemm_a16<<<waves / 4, T, 0, stream>>>(H, W2, XW2, N, NCLS, HID);
    }
    k_agg2<<<(N * 64 + T - 1) / T, T, 0, stream>>>(rowPtr, edata, XW2, dinv, b2, out, N);
}

// Round 5
// 398.660 us; speedup vs baseline: 5.0810x; 1.5808x over previous
//
#include <hip/hip_runtime.h>
#include <hip/hip_bf16.h>

typedef __bf16 bf16_t;
typedef __attribute__((ext_vector_type(8))) __bf16 bf16x8;
typedef __attribute__((ext_vector_type(2))) __bf16 bf16x2;
typedef __attribute__((ext_vector_type(4))) float f32x4;

// ---------------- degree / dinv ----------------
__global__ void k_deg_count(const int* __restrict__ dst, int* __restrict__ deg, int E) {
    int e = blockIdx.x * blockDim.x + threadIdx.x;
    if (e < E) atomicAdd(&deg[dst[e]], 1);
}

__global__ void k_dinv(const int* __restrict__ deg, float* __restrict__ dinv, int n) {
    int i = blockIdx.x * blockDim.x + threadIdx.x;
    if (i < n) dinv[i] = rsqrtf((float)(deg[i] + 1));  // +1 = self loop
}

// ---------------- 3-phase parallel exclusive scan: deg -> rowPtr -----------
// phase 1: per-block (1024 elems) partial sums
__global__ __launch_bounds__(256) void k_scan1(const int* __restrict__ deg,
                                               int* __restrict__ bsum, int n) {
    __shared__ int red[256];
    int b = blockIdx.x, t = threadIdx.x;
    int base = b * 1024 + t * 4;
    int s = 0;
#pragma unroll
    for (int j = 0; j < 4; ++j) { int i = base + j; if (i < n) s += deg[i]; }
    red[t] = s;
    __syncthreads();
    for (int d = 128; d > 0; d >>= 1) {
        if (t < d) red[t] += red[t + d];
        __syncthreads();
    }
    if (t == 0) bsum[b] = red[0];
}

// phase 2: single block scans <=256 block sums (exclusive), writes rowPtr[n]=E
__global__ __launch_bounds__(256) void k_scan2(int* __restrict__ bsum, int nb,
                                               int* __restrict__ rowPtr, int n) {
    __shared__ int s[256];
    int t = threadIdx.x;
    int v = (t < nb) ? bsum[t] : 0;
    s[t] = v;
    __syncthreads();
    for (int d = 1; d < 256; d <<= 1) {   // Hillis-Steele inclusive
        int u = (t >= d) ? s[t - d] : 0;
        __syncthreads();
        s[t] += u;
        __syncthreads();
    }
    if (t < nb) bsum[t] = s[t] - v;       // exclusive block offset
    if (t == 255) rowPtr[n] = s[255];     // total = E
}

// phase 3: block-local exclusive scan + block offset -> rowPtr
__global__ __launch_bounds__(256) void k_scan3(const int* __restrict__ deg,
                                               const int* __restrict__ bsum,
                                               int* __restrict__ rowPtr, int n) {
    __shared__ int red[256];
    int b = blockIdx.x, t = threadIdx.x;
    int base = b * 1024 + t * 4;
    int v[4]; int s = 0;
#pragma unroll
    for (int j = 0; j < 4; ++j) { int i = base + j; v[j] = (i < n) ? deg[i] : 0; s += v[j]; }
    red[t] = s;
    __syncthreads();
    for (int d = 1; d < 256; d <<= 1) {
        int u = (t >= d) ? red[t - d] : 0;
        __syncthreads();
        red[t] += u;
        __syncthreads();
    }
    int run = bsum[b] + red[t] - s;       // exclusive offset for this thread's 4
#pragma unroll
    for (int j = 0; j < 4; ++j) { int i = base + j; if (i < n) rowPtr[i] = run; run += v[j]; }
}

// ---------------- scatter edges into CSR, payload = {src, nrm} ------------
__global__ void k_scatter(const int* __restrict__ src, const int* __restrict__ dst,
                          const float* __restrict__ dinv, const int* __restrict__ rowPtr,
                          int* __restrict__ cursor, int2* __restrict__ edata, int E) {
    int e = blockIdx.x * blockDim.x + threadIdx.x;
    if (e >= E) return;
    int s = src[e], d = dst[e];
    int pos = rowPtr[d] + atomicAdd(&cursor[d], 1);
    int2 p; p.x = s; p.y = __float_as_int(dinv[s] * dinv[d]);
    edata[pos] = p;
}

// ------- pack B[K,N] f32 -> bf16 MFMA fragments -------------------------
// Bp[((s*(N/16)+t)*64 + lane)*8 + j] = bf16(B[(s*32 + (lane>>4)*8 + j)*N + t*16 + (lane&15)])
__global__ void k_packB(const float* __restrict__ B, bf16_t* __restrict__ Bp,
                        int K, int N) {
    int idx = blockIdx.x * blockDim.x + threadIdx.x;
    int total = (K >> 5) * (N >> 4) * 512;
    if (idx >= total) return;
    int j    = idx & 7;
    int lane = (idx >> 3) & 63;
    int st   = idx >> 9;
    int nt   = N >> 4;
    int s = st / nt, t = st - s * nt;
    int k = s * 32 + (lane >> 4) * 8 + j;
    int n = t * 16 + (lane & 15);
    Bp[idx] = (bf16_t)B[(size_t)k * N + n];
}

// ------- GEMM with packed B: one wave per 16-row strip, full N ------------
// MFMA 16x16x32 (HW-verified): A[m=lane&15][k=quad*8+j], D: col=lane&15,row=quad*4+reg
template <int KSTEPS, int NTILES>
__global__ __launch_bounds__(256) void k_gemm_pf32(
        const float* __restrict__ A, const bf16_t* __restrict__ Bp,
        bf16_t* __restrict__ C, int M) {
    int wave = (blockIdx.x * blockDim.x + threadIdx.x) >> 6;
    if (wave * 16 >= M) return;
    int lane = threadIdx.x & 63;
    int r16 = lane & 15, quad = lane >> 4;
    const int K = KSTEPS * 32, N = NTILES * 16;
    f32x4 acc[NTILES] = {};
    const float* arow = A + (size_t)(wave * 16 + r16) * K + quad * 8;
#pragma unroll
    for (int s = 0; s < KSTEPS; ++s) {
        const float* ap = arow + s * 32;
        bf16x8 a;
#pragma unroll
        for (int j = 0; j < 8; ++j) a[j] = (bf16_t)ap[j];
        const bf16_t* bp = Bp + ((size_t)(s * NTILES) * 64 + lane) * 8;
#pragma unroll
        for (int t = 0; t < NTILES; ++t) {
            bf16x8 b = *(const bf16x8*)(bp + t * 512);
            acc[t] = __builtin_amdgcn_mfma_f32_16x16x32_bf16(a, b, acc[t], 0, 0, 0);
        }
    }
#pragma unroll
    for (int t = 0; t < NTILES; ++t)
#pragma unroll
        for (int r = 0; r < 4; ++r)
            C[(size_t)(wave * 16 + quad * 4 + r) * N + t * 16 + r16] = (bf16_t)acc[t][r];
}

// same, A in bf16 (layer 2: A = H)
template <int KSTEPS, int NTILES>
__global__ __launch_bounds__(256) void k_gemm_pa16(
        const bf16_t* __restrict__ A, const bf16_t* __restrict__ Bp,
        bf16_t* __restrict__ C, int M) {
    int wave = (blockIdx.x * blockDim.x + threadIdx.x) >> 6;
    if (wave * 16 >= M) return;
    int lane = threadIdx.x & 63;
    int r16 = lane & 15, quad = lane >> 4;
    const int K = KSTEPS * 32, N = NTILES * 16;
    f32x4 acc[NTILES] = {};
    const bf16_t* arow = A + (size_t)(wave * 16 + r16) * K + quad * 8;
#pragma unroll
    for (int s = 0; s < KSTEPS; ++s) {
        bf16x8 a = *(const bf16x8*)(arow + s * 32);
        const bf16_t* bp = Bp + ((size_t)(s * NTILES) * 64 + lane) * 8;
#pragma unroll
        for (int t = 0; t < NTILES; ++t) {
            bf16x8 b = *(const bf16x8*)(bp + t * 512);
            acc[t] = __builtin_amdgcn_mfma_f32_16x16x32_bf16(a, b, acc[t], 0, 0, 0);
        }
    }
#pragma unroll
    for (int t = 0; t < NTILES; ++t)
#pragma unroll
        for (int r = 0; r < 4; ++r)
            C[(size_t)(wave * 16 + quad * 4 + r) * N + t * 16 + r16] = (bf16_t)acc[t][r];
}

// ------- layer-1 aggregate (CSR): one wave per node, 2 feats/lane ---------
__global__ __launch_bounds__(256) void k_agg1(
        const int* __restrict__ rowPtr, const int2* __restrict__ edata,
        const bf16_t* __restrict__ XW1, const float* __restrict__ dinv,
        const float* __restrict__ b1, bf16_t* __restrict__ H, int n) {
    int wave = (blockIdx.x * blockDim.x + threadIdx.x) >> 6;
    if (wave >= n) return;
    int lane = threadIdx.x & 63;
    int f = lane << 1;
    int r0 = rowPtr[wave], r1 = rowPtr[wave + 1];
    float a0 = 0.f, a1 = 0.f, c0 = 0.f, c1 = 0.f;
    int k = r0;
    for (; k + 1 < r1; k += 2) {
        int2 e0 = edata[k], e1 = edata[k + 1];
        float w0 = __int_as_float(e0.y), w1 = __int_as_float(e1.y);
        bf16x2 x0 = *(const bf16x2*)(XW1 + ((size_t)e0.x << 7) + f);
        bf16x2 x1 = *(const bf16x2*)(XW1 + ((size_t)e1.x << 7) + f);
        a0 += (float)x0[0] * w0; a1 += (float)x0[1] * w0;
        c0 += (float)x1[0] * w1; c1 += (float)x1[1] * w1;
    }
    if (k < r1) {
        int2 e0 = edata[k];
        float w0 = __int_as_float(e0.y);
        bf16x2 x0 = *(const bf16x2*)(XW1 + ((size_t)e0.x << 7) + f);
        a0 += (float)x0[0] * w0; a1 += (float)x0[1] * w0;
    }
    float d = dinv[wave], d2 = d * d;
    bf16x2 xs = *(const bf16x2*)(XW1 + ((size_t)wave << 7) + f);
    float v0 = a0 + c0 + (float)xs[0] * d2 + b1[f];
    float v1 = a1 + c1 + (float)xs[1] * d2 + b1[f + 1];
    bf16x2 h;
    h[0] = (bf16_t)fmaxf(v0, 0.f);
    h[1] = (bf16_t)fmaxf(v1, 0.f);
    *(bf16x2*)(H + ((size_t)wave << 7) + f) = h;
}

// ------- layer-2 aggregate + log_softmax: one wave per node ----------------
__global__ __launch_bounds__(256) void k_agg2(
        const int* __restrict__ rowPtr, const int2* __restrict__ edata,
        const bf16_t* __restrict__ XW2, const float* __restrict__ dinv,
        const float* __restrict__ b2, float* __restrict__ out, int n) {
    int wave = (blockIdx.x * blockDim.x + threadIdx.x) >> 6;
    if (wave >= n) return;
    int lane = threadIdx.x & 63;
    int f = lane & 31, h = lane >> 5;
    int r0 = rowPtr[wave], r1 = rowPtr[wave + 1];
    float acc = 0.f;
    for (int k = r0 + h; k < r1; k += 2) {
        int2 e = edata[k];
        float w = __int_as_float(e.y);
        acc += (float)XW2[((size_t)e.x << 5) + f] * w;
    }
    acc += __shfl_xor(acc, 32);
    float d = dinv[wave];
    float v = acc + (float)XW2[((size_t)wave << 5) + f] * d * d + b2[f];
    float mx = v;
#pragma unroll
    for (int m = 16; m >= 1; m >>= 1) mx = fmaxf(mx, __shfl_xor(mx, m));
    float s = expf(v - mx);
#pragma unroll
    for (int m = 16; m >= 1; m >>= 1) s += __shfl_xor(s, m);
    if (lane < 32) out[((size_t)wave << 5) + f] = v - mx - logf(s);
}

extern "C" void kernel_launch(void* const* d_in, const int* in_sizes, int n_in,
                              void* d_out, int out_size, void* d_ws, size_t ws_size,
                              hipStream_t stream) {
    const float* feat = (const float*)d_in[0];
    const int*   eidx = (const int*)d_in[1];
    const float* W1   = (const float*)d_in[2];
    const float* b1   = (const float*)d_in[3];
    const float* W2   = (const float*)d_in[4];
    const float* b2   = (const float*)d_in[5];
    float* out = (float*)d_out;

    const int FIN = 256, HID = 128, NCLS = 32;
    const int N = in_sizes[0] / FIN;   // 100000
    const int E = in_sizes[1] / 2;     // 800000
    const int* src = eidx;
    const int* dst = eidx + E;

    // workspace carve-up (256B aligned), ~59 MB total
    char* ws = (char*)d_ws;
    size_t o = 0;
    auto alloc = [&](size_t bytes) -> void* {
        void* p = ws + o;
        o = (o + bytes + 255) & ~(size_t)255;
        return p;
    };
    int*    deg    = (int*)   alloc((size_t)N * 4);
    float*  dinv   = (float*) alloc((size_t)N * 4);
    int*    rowPtr = (int*)   alloc((size_t)(N + 1) * 4);
    int*    cursor = (int*)   alloc((size_t)N * 4);
    int*    bsum   = (int*)   alloc(256 * 4);
    bf16_t* Bp1    = (bf16_t*)alloc((size_t)(FIN / 32) * (HID / 16) * 512 * 2); // 64 KB
    bf16_t* Bp2    = (bf16_t*)alloc((size_t)(HID / 32) * (NCLS / 16) * 512 * 2); // 8 KB
    int2*   edata  = (int2*)  alloc((size_t)E * 8);        // 6.4 MB
    bf16_t* XW1    = (bf16_t*)alloc((size_t)N * HID * 2);  // 25.6 MB
    bf16_t* H      = (bf16_t*)alloc((size_t)N * HID * 2);  // 25.6 MB
    bf16_t* XW2    = XW1;   // alias: XW1 dead after k_agg1

    const int T = 256;
    const int NB = (N + 1023) >> 10;   // 98 scan blocks (<=256)
    hipMemsetAsync(deg, 0, (size_t)N * 4, stream);
    hipMemsetAsync(cursor, 0, (size_t)N * 4, stream);
    k_deg_count<<<(E + T - 1) / T, T, 0, stream>>>(dst, deg, E);
    k_dinv     <<<(N + T - 1) / T, T, 0, stream>>>(deg, dinv, N);
    k_scan1    <<<NB, T, 0, stream>>>(deg, bsum, N);
    k_scan2    <<<1, T, 0, stream>>>(bsum, NB, rowPtr, N);
    k_scan3    <<<NB, T, 0, stream>>>(deg, bsum, rowPtr, N);
    k_scatter  <<<(E + T - 1) / T, T, 0, stream>>>(src, dst, dinv, rowPtr, cursor, edata, E);

    // pack weights into MFMA fragment order (bf16)
    k_packB<<<((FIN / 32) * (HID / 16) * 512 + T - 1) / T, T, 0, stream>>>(W1, Bp1, FIN, HID);
    k_packB<<<((HID / 32) * (NCLS / 16) * 512 + T - 1) / T, T, 0, stream>>>(W2, Bp2, HID, NCLS);

    // layer 1: XW1 = bf16(feat @ W1)   (6250 waves, wave = 16 rows x 128 cols)
    {
        int waves = (N + 15) / 16;
        k_gemm_pf32<8, 8><<<(waves * 64 + T - 1) / T, T, 0, stream>>>(feat, Bp1, XW1, N);
    }
    k_agg1<<<(N * 64 + T - 1) / T, T, 0, stream>>>(rowPtr, edata, XW1, dinv, b1, H, N);

    // layer 2: XW2 = bf16(H @ W2)      (6250 waves, wave = 16 rows x 32 cols)
    {
        int waves = (N + 15) / 16;
        k_gemm_pa16<4, 2><<<(waves * 64 + T - 1) / T, T, 0, stream>>>(H, Bp2, XW2, N);
    }
    k_agg2<<<(N * 64 + T - 1) / T, T, 0, stream>>>(rowPtr, edata, XW2, dinv, b2, out, N);
}

// Round 7
// 370.258 us; speedup vs baseline: 5.4708x; 1.0767x over previous
//
#include <hip/hip_runtime.h>
#include <hip/hip_bf16.h>

typedef __bf16 bf16_t;
typedef __attribute__((ext_vector_type(8))) __bf16 bf16x8;
typedef __attribute__((ext_vector_type(4))) float f32x4;

// ---------------- degree ----------------
__global__ void k_deg_count(const int* __restrict__ dst, int* __restrict__ deg, int E) {
    int e = blockIdx.x * blockDim.x + threadIdx.x;
    if (e < E) atomicAdd(&deg[dst[e]], 1);
}

// ---------------- dinv + scan phase 1 (fused) -----------------------------
__global__ __launch_bounds__(256) void k_dinv_scan1(const int* __restrict__ deg,
                                                    float* __restrict__ dinv,
                                                    int* __restrict__ bsum, int n) {
    __shared__ int red[256];
    int b = blockIdx.x, t = threadIdx.x;
    int base = b * 1024 + t * 4;
    int s = 0;
#pragma unroll
    for (int j = 0; j < 4; ++j) {
        int i = base + j;
        if (i < n) { int d = deg[i]; s += d; dinv[i] = rsqrtf((float)(d + 1)); }
    }
    red[t] = s;
    __syncthreads();
    for (int d = 128; d > 0; d >>= 1) {
        if (t < d) red[t] += red[t + d];
        __syncthreads();
    }
    if (t == 0) bsum[b] = red[0];
}

// phase 2: single block scans <=256 block sums (exclusive), writes rowPtr[n]=E
__global__ __launch_bounds__(256) void k_scan2(int* __restrict__ bsum, int nb,
                                               int* __restrict__ rowPtr, int n) {
    __shared__ int s[256];
    int t = threadIdx.x;
    int v = (t < nb) ? bsum[t] : 0;
    s[t] = v;
    __syncthreads();
    for (int d = 1; d < 256; d <<= 1) {   // Hillis-Steele inclusive
        int u = (t >= d) ? s[t - d] : 0;
        __syncthreads();
        s[t] += u;
        __syncthreads();
    }
    if (t < nb) bsum[t] = s[t] - v;       // exclusive block offset
    if (t == 255) rowPtr[n] = s[255];     // total = E
}

// phase 3: block-local exclusive scan + block offset -> rowPtr
__global__ __launch_bounds__(256) void k_scan3(const int* __restrict__ deg,
                                               const int* __restrict__ bsum,
                                               int* __restrict__ rowPtr, int n) {
    __shared__ int red[256];
    int b = blockIdx.x, t = threadIdx.x;
    int base = b * 1024 + t * 4;
    int v[4]; int s = 0;
#pragma unroll
    for (int j = 0; j < 4; ++j) { int i = base + j; v[j] = (i < n) ? deg[i] : 0; s += v[j]; }
    red[t] = s;
    __syncthreads();
    for (int d = 1; d < 256; d <<= 1) {
        int u = (t >= d) ? red[t - d] : 0;
        __syncthreads();
        red[t] += u;
        __syncthreads();
    }
    int run = bsum[b] + red[t] - s;
#pragma unroll
    for (int j = 0; j < 4; ++j) { int i = base + j; if (i < n) rowPtr[i] = run; run += v[j]; }
}

// ---------------- scatter edges into CSR, payload = {src, nrm} ------------
__global__ void k_scatter(const int* __restrict__ src, const int* __restrict__ dst,
                          const float* __restrict__ dinv, const int* __restrict__ rowPtr,
                          int* __restrict__ cursor, int2* __restrict__ edata, int E) {
    int e = blockIdx.x * blockDim.x + threadIdx.x;
    if (e >= E) return;
    int s = src[e], d = dst[e];
    int pos = rowPtr[d] + atomicAdd(&cursor[d], 1);
    int2 p; p.x = s; p.y = __float_as_int(dinv[s] * dinv[d]);
    edata[pos] = p;
}

// ------- pack B[K,N] f32 -> bf16 MFMA fragments (both weights, 1 launch) --
__device__ inline void packB_one(const float* __restrict__ B, bf16_t* __restrict__ Bp,
                                 int N, int idx) {
    int j    = idx & 7;
    int lane = (idx >> 3) & 63;
    int st   = idx >> 9;
    int nt   = N >> 4;
    int s = st / nt, t = st - s * nt;
    int k = s * 32 + (lane >> 4) * 8 + j;
    int n = t * 16 + (lane & 15);
    Bp[idx] = (bf16_t)B[(size_t)k * N + n];
}

__global__ void k_packBoth(const float* __restrict__ W1, bf16_t* __restrict__ Bp1,
                           const float* __restrict__ W2, bf16_t* __restrict__ Bp2) {
    int idx = blockIdx.x * blockDim.x + threadIdx.x;
    const int T1 = (256 / 32) * (128 / 16) * 512;   // 32768
    const int T2 = (128 / 32) * (32 / 16) * 512;    // 4096
    if (idx < T1) packB_one(W1, Bp1, 128, idx);
    else if (idx < T1 + T2) packB_one(W2, Bp2, 32, idx - T1);
}

// ------- GEMM with packed B: one wave per 16-row strip, full N ------------
// MFMA 16x16x32 (HW-verified): A[m=lane&15][k=quad*8+j], D: col=lane&15,row=quad*4+reg
template <int KSTEPS, int NTILES>
__global__ __launch_bounds__(256) void k_gemm_pf32(
        const float* __restrict__ A, const bf16_t* __restrict__ Bp,
        bf16_t* __restrict__ C, int M) {
    int wave = (blockIdx.x * blockDim.x + threadIdx.x) >> 6;
    if (wave * 16 >= M) return;
    int lane = threadIdx.x & 63;
    int r16 = lane & 15, quad = lane >> 4;
    const int K = KSTEPS * 32, N = NTILES * 16;
    f32x4 acc[NTILES] = {};
    const float* arow = A + (size_t)(wave * 16 + r16) * K + quad * 8;
#pragma unroll
    for (int s = 0; s < KSTEPS; ++s) {
        const float* ap = arow + s * 32;
        bf16x8 a;
#pragma unroll
        for (int j = 0; j < 8; ++j) a[j] = (bf16_t)ap[j];
        const bf16_t* bp = Bp + ((size_t)(s * NTILES) * 64 + lane) * 8;
#pragma unroll
        for (int t = 0; t < NTILES; ++t) {
            bf16x8 b = *(const bf16x8*)(bp + t * 512);
            acc[t] = __builtin_amdgcn_mfma_f32_16x16x32_bf16(a, b, acc[t], 0, 0, 0);
        }
    }
#pragma unroll
    for (int t = 0; t < NTILES; ++t)
#pragma unroll
        for (int r = 0; r < 4; ++r)
            C[(size_t)(wave * 16 + quad * 4 + r) * N + t * 16 + r16] = (bf16_t)acc[t][r];
}

template <int KSTEPS, int NTILES>
__global__ __launch_bounds__(256) void k_gemm_pa16(
        const bf16_t* __restrict__ A, const bf16_t* __restrict__ Bp,
        bf16_t* __restrict__ C, int M) {
    int wave = (blockIdx.x * blockDim.x + threadIdx.x) >> 6;
    if (wave * 16 >= M) return;
    int lane = threadIdx.x & 63;
    int r16 = lane & 15, quad = lane >> 4;
    const int K = KSTEPS * 32, N = NTILES * 16;
    f32x4 acc[NTILES] = {};
    const bf16_t* arow = A + (size_t)(wave * 16 + r16) * K + quad * 8;
#pragma unroll
    for (int s = 0; s < KSTEPS; ++s) {
        bf16x8 a = *(const bf16x8*)(arow + s * 32);
        const bf16_t* bp = Bp + ((size_t)(s * NTILES) * 64 + lane) * 8;
#pragma unroll
        for (int t = 0; t < NTILES; ++t) {
            bf16x8 b = *(const bf16x8*)(bp + t * 512);
            acc[t] = __builtin_amdgcn_mfma_f32_16x16x32_bf16(a, b, acc[t], 0, 0, 0);
        }
    }
#pragma unroll
    for (int t = 0; t < NTILES; ++t)
#pragma unroll
        for (int r = 0; r < 4; ++r)
            C[(size_t)(wave * 16 + quad * 4 + r) * N + t * 16 + r16] = (bf16_t)acc[t][r];
}

// ------- layer-1 aggregate: 16 lanes x bf16x8, 4 parity streams, 2-unroll -
// No cross-lane ops inside the (divergent) loop; convergent shfl_xor after.
// H[i] = relu( sum_e nrm*XW1[src] + dinv[i]^2*XW1[i] + b1 ), bf16 out
__global__ __launch_bounds__(256) void k_agg1(
        const int* __restrict__ rowPtr, const int2* __restrict__ edata,
        const bf16_t* __restrict__ XW1, const float* __restrict__ dinv,
        const float* __restrict__ b1, bf16_t* __restrict__ H, int n) {
    int wave = (blockIdx.x * blockDim.x + threadIdx.x) >> 6;
    if (wave >= n) return;
    int lane = threadIdx.x & 63;
    int fl = (lane & 15) << 3;   // 8 features
    int h  = lane >> 4;          // parity stream 0..3
    int r0 = rowPtr[wave], r1 = rowPtr[wave + 1];
    float a0[8] = {}, a1[8] = {};
    int k = r0 + h;
    for (; k + 4 < r1; k += 8) {          // 2 independent gathers in flight
        int2 e0 = edata[k], e1 = edata[k + 4];
        float w0 = __int_as_float(e0.y), w1 = __int_as_float(e1.y);
        bf16x8 x0 = *(const bf16x8*)(XW1 + ((size_t)e0.x << 7) + fl);
        bf16x8 x1 = *(const bf16x8*)(XW1 + ((size_t)e1.x << 7) + fl);
#pragma unroll
        for (int j = 0; j < 8; ++j) { a0[j] += (float)x0[j] * w0; a1[j] += (float)x1[j] * w1; }
    }
    if (k < r1) {
        int2 e0 = edata[k];
        float w0 = __int_as_float(e0.y);
        bf16x8 x0 = *(const bf16x8*)(XW1 + ((size_t)e0.x << 7) + fl);
#pragma unroll
        for (int j = 0; j < 8; ++j) a0[j] += (float)x0[j] * w0;
    }
#pragma unroll
    for (int j = 0; j < 8; ++j) {        // convergent reduction over 4 streams
        a0[j] += a1[j];
        a0[j] += __shfl_xor(a0[j], 16);
        a0[j] += __shfl_xor(a0[j], 32);
    }
    if (h == 0) {
        float d = dinv[wave], d2 = d * d;
        bf16x8 xs = *(const bf16x8*)(XW1 + ((size_t)wave << 7) + fl);
        bf16x8 hv;
#pragma unroll
        for (int j = 0; j < 8; ++j) {
            float v = a0[j] + (float)xs[j] * d2 + b1[fl + j];
            hv[j] = (bf16_t)fmaxf(v, 0.f);
        }
        *(bf16x8*)(H + ((size_t)wave << 7) + fl) = hv;
    }
}

// ------- layer-2 aggregate + log_softmax: 1 class/lane, 2 streams, 2-unroll
__global__ __launch_bounds__(256) void k_agg2(
        const int* __restrict__ rowPtr, const int2* __restrict__ edata,
        const bf16_t* __restrict__ XW2, const float* __restrict__ dinv,
        const float* __restrict__ b2, float* __restrict__ out, int n) {
    int wave = (blockIdx.x * blockDim.x + threadIdx.x) >> 6;
    if (wave >= n) return;
    int lane = threadIdx.x & 63;
    int f = lane & 31, h = lane >> 5;
    int r0 = rowPtr[wave], r1 = rowPtr[wave + 1];
    float acc0 = 0.f, acc1 = 0.f;
    int k = r0 + h;
    for (; k + 2 < r1; k += 4) {
        int2 e0 = edata[k], e1 = edata[k + 2];
        acc0 += (float)XW2[((size_t)e0.x << 5) + f] * __int_as_float(e0.y);
        acc1 += (float)XW2[((size_t)e1.x << 5) + f] * __int_as_float(e1.y);
    }
    if (k < r1) {
        int2 e0 = edata[k];
        acc0 += (float)XW2[((size_t)e0.x << 5) + f] * __int_as_float(e0.y);
    }
    float acc = acc0 + acc1;
    acc += __shfl_xor(acc, 32);          // convergent: combine the 2 streams
    float d = dinv[wave];
    float v = acc + (float)XW2[((size_t)wave << 5) + f] * d * d + b2[f];
    float mx = v;
#pragma unroll
    for (int m = 16; m >= 1; m >>= 1) mx = fmaxf(mx, __shfl_xor(mx, m));
    float s = expf(v - mx);
#pragma unroll
    for (int m = 16; m >= 1; m >>= 1) s += __shfl_xor(s, m);
    if (lane < 32) out[((size_t)wave << 5) + f] = v - mx - logf(s);
}

extern "C" void kernel_launch(void* const* d_in, const int* in_sizes, int n_in,
                              void* d_out, int out_size, void* d_ws, size_t ws_size,
                              hipStream_t stream) {
    const float* feat = (const float*)d_in[0];
    const int*   eidx = (const int*)d_in[1];
    const float* W1   = (const float*)d_in[2];
    const float* b1   = (const float*)d_in[3];
    const float* W2   = (const float*)d_in[4];
    const float* b2   = (const float*)d_in[5];
    float* out = (float*)d_out;

    const int FIN = 256, HID = 128, NCLS = 32;
    const int N = in_sizes[0] / FIN;   // 100000
    const int E = in_sizes[1] / 2;     // 800000
    const int* src = eidx;
    const int* dst = eidx + E;

    // workspace carve-up (256B aligned)
    char* ws = (char*)d_ws;
    size_t o = 0;
    auto alloc = [&](size_t bytes) -> void* {
        void* p = ws + o;
        o = (o + bytes + 255) & ~(size_t)255;
        return p;
    };
    int*    deg    = (int*)   alloc((size_t)N * 4);   // deg+cursor adjacent:
    int*    cursor = (int*)   alloc((size_t)N * 4);   // single memset below
    size_t  zlen   = (size_t)((char*)(cursor + N) - (char*)deg);
    float*  dinv   = (float*) alloc((size_t)N * 4);
    int*    rowPtr = (int*)   alloc((size_t)(N + 1) * 4);
    int*    bsum   = (int*)   alloc(256 * 4);
    bf16_t* Bp1    = (bf16_t*)alloc((size_t)(FIN / 32) * (HID / 16) * 512 * 2);
    bf16_t* Bp2    = (bf16_t*)alloc((size_t)(HID / 32) * (NCLS / 16) * 512 * 2);
    int2*   edata  = (int2*)  alloc((size_t)E * 8);        // 6.4 MB
    bf16_t* XW1    = (bf16_t*)alloc((size_t)N * HID * 2);  // 25.6 MB
    bf16_t* H      = (bf16_t*)alloc((size_t)N * HID * 2);  // 25.6 MB
    bf16_t* XW2    = XW1;   // alias: XW1 dead after k_agg1

    const int T = 256;
    const int NB = (N + 1023) >> 10;   // 98 scan blocks (<=256)
    hipMemsetAsync(deg, 0, zlen, stream);
    k_deg_count <<<(E + T - 1) / T, T, 0, stream>>>(dst, deg, E);
    k_dinv_scan1<<<NB, T, 0, stream>>>(deg, dinv, bsum, N);
    k_scan2     <<<1, T, 0, stream>>>(bsum, NB, rowPtr, N);
    k_scan3     <<<NB, T, 0, stream>>>(deg, bsum, rowPtr, N);
    k_scatter   <<<(E + T - 1) / T, T, 0, stream>>>(src, dst, dinv, rowPtr, cursor, edata, E);
    k_packBoth  <<<(32768 + 4096 + T - 1) / T, T, 0, stream>>>(W1, Bp1, W2, Bp2);

    // layer 1: XW1 = bf16(feat @ W1)   (wave = 16 rows x 128 cols)
    {
        int waves = (N + 15) / 16;
        k_gemm_pf32<8, 8><<<(waves * 64 + T - 1) / T, T, 0, stream>>>(feat, Bp1, XW1, N);
    }
    k_agg1<<<(N * 64 + T - 1) / T, T, 0, stream>>>(rowPtr, edata, XW1, dinv, b1, H, N);

    // layer 2: XW2 = bf16(H @ W2)      (wave = 16 rows x 32 cols)
    {
        int waves = (N + 15) / 16;
        k_gemm_pa16<4, 2><<<(waves * 64 + T - 1) / T, T, 0, stream>>>(H, Bp2, XW2, N);
    }
    k_agg2<<<(N * 64 + T - 1) / T, T, 0, stream>>>(rowPtr, edata, XW2, dinv, b2, out, N);
}